// Round 2
// baseline (319.774 us; speedup 1.0000x reference)
//
#include <hip/hip_runtime.h>
#include <hip/hip_bf16.h>

#define NBANK 131072
#define DF 1024
#define NB 64

typedef float f32x4 __attribute__((ext_vector_type(4)));
typedef short bf16x8 __attribute__((ext_vector_type(8)));

__device__ __forceinline__ unsigned short f2bf(float f) {
    union { float f; unsigned u; } c; c.f = f;
    unsigned u = c.u;
    return (unsigned short)((u + 0x7FFFu + ((u >> 16) & 1u)) >> 16);
}

// Kernel A: L2-normalize the 64 input rows.
// Writes x_f32 (for the scatter update) and bf16 A-fragments pre-permuted
// into MFMA lane order: frag[(m>>4)*32 + ks][lane = (t&3)*16 + (m&15)].
__global__ __launch_bounds__(128) void knorm(const float* __restrict__ inputs,
                                             float* __restrict__ x_f32,
                                             bf16x8* __restrict__ xfrag) {
    int m = blockIdx.x;
    int t = threadIdx.x;          // handles k = t*8 .. t*8+7
    const f32x4* row = (const f32x4*)(inputs + (size_t)m * DF);
    f32x4 v0 = row[t * 2];
    f32x4 v1 = row[t * 2 + 1];
    float s = v0.x*v0.x + v0.y*v0.y + v0.z*v0.z + v0.w*v0.w
            + v1.x*v1.x + v1.y*v1.y + v1.z*v1.z + v1.w*v1.w;
    for (int o = 32; o > 0; o >>= 1) s += __shfl_xor(s, o);
    __shared__ float red[2];
    if ((t & 63) == 0) red[t >> 6] = s;
    __syncthreads();
    float tot = red[0] + red[1];
    float inv = 1.0f / fmaxf(sqrtf(tot), 1e-12f);
    v0 *= inv; v1 *= inv;
    f32x4* xr = (f32x4*)(x_f32 + (size_t)m * DF);
    xr[t * 2]     = v0;
    xr[t * 2 + 1] = v1;
    unsigned short h[8] = { f2bf(v0.x), f2bf(v0.y), f2bf(v0.z), f2bf(v0.w),
                            f2bf(v1.x), f2bf(v1.y), f2bf(v1.z), f2bf(v1.w) };
    int idx = ((m >> 4) * 32 + (t >> 2)) * 64 + (t & 3) * 16 + (m & 15);
    xfrag[idx] = *(bf16x8*)h;
}

// Kernel B: fused sim GEMM + bank copy + sequential momentum update.
// No LDS, no barriers. Each wave owns 16 bank rows. B-fragments are loaded
// directly from global: lane l reads row (wrow0 + (l&15)), f32 cols
// ks*32 + (l>>4)*8 .. +7 -- lanes (r, r+16, r+32, r+48) together cover one
// contiguous 128B segment of row r (full line utilization). The same
// registers feed the verbatim f32 copy to outf and the bf16 MFMA B operand.
// Streaming accesses are nontemporal so xfrag (A, re-read by all waves)
// stays L2-resident. Waves owning rows in `indexes` skip the plain copy and
// replay the exact sequential momentum chain instead.
__global__ __launch_bounds__(256, 4) void kmain(const float* __restrict__ features,
                                                const bf16x8* __restrict__ xfrag,
                                                const int* __restrict__ indexes,
                                                const float* __restrict__ x_f32,
                                                float* __restrict__ sim,
                                                float* __restrict__ outf) {
    int wave = threadIdx.x >> 6;
    int lane = threadIdx.x & 63;
    int wrow0 = blockIdx.x * 64 + wave * 16;   // this wave's 16 bank rows
    int r  = lane & 15;
    int kg = lane >> 4;

    // which of my 16 rows appear in indexes? (uniform per wave)
    unsigned urmask = 0;
#pragma unroll 4
    for (int j = 0; j < NB; ++j) {
        unsigned d = (unsigned)(indexes[j] - wrow0);
        if (d < 16u) urmask |= (1u << d);
    }
    bool docopy = !((urmask >> r) & 1);

    const float* brow = features + (size_t)(wrow0 + r) * DF + kg * 8;
    float*       orow = outf     + (size_t)(wrow0 + r) * DF + kg * 8;

    f32x4 acc[4] = {{0.f,0.f,0.f,0.f},{0.f,0.f,0.f,0.f},
                    {0.f,0.f,0.f,0.f},{0.f,0.f,0.f,0.f}};
#pragma unroll 2
    for (int ks = 0; ks < 32; ++ks) {
        f32x4 b0 = __builtin_nontemporal_load((const f32x4*)(brow + ks * 32));
        f32x4 b1 = __builtin_nontemporal_load((const f32x4*)(brow + ks * 32) + 1);
        if (docopy) {
            __builtin_nontemporal_store(b0, (f32x4*)(orow + ks * 32));
            __builtin_nontemporal_store(b1, (f32x4*)(orow + ks * 32) + 1);
        }
        unsigned short h[8] = { f2bf(b0.x), f2bf(b0.y), f2bf(b0.z), f2bf(b0.w),
                                f2bf(b1.x), f2bf(b1.y), f2bf(b1.z), f2bf(b1.w) };
        bf16x8 b = *(bf16x8*)h;
#pragma unroll
        for (int mt = 0; mt < 4; ++mt) {
            bf16x8 a = xfrag[(size_t)(mt * 32 + ks) * 64 + lane];
            acc[mt] = __builtin_amdgcn_mfma_f32_16x16x32_bf16(a, b, acc[mt], 0, 0, 0);
        }
    }

    // sim epilogue: m = mt*16 + kg*4 + rr, n = wrow0 + r
#pragma unroll
    for (int mt = 0; mt < 4; ++mt)
#pragma unroll
        for (int rr = 0; rr < 4; ++rr)
            __builtin_nontemporal_store(acc[mt][rr] * 20.0f,
                sim + (size_t)(mt * 16 + kg * 4 + rr) * NBANK + wrow0 + r);

    // sequential momentum chain for owned update rows (exact scan order)
    if (urmask) {
        for (int p = 0; p < 16; ++p) {
            if (!((urmask >> p) & 1)) continue;
            int row = wrow0 + p;
            const f32x4* fr = (const f32x4*)(features + (size_t)row * DF) + lane * 4;
            f32x4 c0 = fr[0], c1 = fr[1], c2 = fr[2], c3 = fr[3];
            for (int j = 0; j < NB; ++j) {
                if (indexes[j] != row) continue;   // uniform
                const f32x4* xr = (const f32x4*)(x_f32 + (size_t)j * DF) + lane * 4;
                c0 = c0 * 0.2f + xr[0] * 0.8f;
                c1 = c1 * 0.2f + xr[1] * 0.8f;
                c2 = c2 * 0.2f + xr[2] * 0.8f;
                c3 = c3 * 0.2f + xr[3] * 0.8f;
                float s = c0.x*c0.x + c0.y*c0.y + c0.z*c0.z + c0.w*c0.w
                        + c1.x*c1.x + c1.y*c1.y + c1.z*c1.z + c1.w*c1.w
                        + c2.x*c2.x + c2.y*c2.y + c2.z*c2.z + c2.w*c2.w
                        + c3.x*c3.x + c3.y*c3.y + c3.z*c3.z + c3.w*c3.w;
                for (int o = 32; o > 0; o >>= 1) s += __shfl_xor(s, o);
                float inv = 1.0f / fmaxf(sqrtf(s), 1e-12f);
                c0 *= inv; c1 *= inv; c2 *= inv; c3 *= inv;
            }
            f32x4* orow2 = (f32x4*)(outf + (size_t)row * DF) + lane * 4;
            orow2[0] = c0; orow2[1] = c1; orow2[2] = c2; orow2[3] = c3;
        }
    }
}

extern "C" void kernel_launch(void* const* d_in, const int* in_sizes, int n_in,
                              void* d_out, int out_size, void* d_ws, size_t ws_size,
                              hipStream_t stream) {
    const float* inputs   = (const float*)d_in[0];
    const int*   indexes  = (const int*)d_in[1];
    const float* features = (const float*)d_in[2];
    float* sim  = (float*)d_out;                       // [64 * 131072]
    float* outf = sim + (size_t)NB * NBANK;            // [131072 * 1024]
    float*  x_f32 = (float*)d_ws;                      // 256 KB
    bf16x8* xfrag = (bf16x8*)((char*)d_ws + (size_t)NB * DF * 4);  // 128 KB

    knorm<<<NB, 128, 0, stream>>>(inputs, x_f32, xfrag);
    kmain<<<NBANK / 64, 256, 0, stream>>>(features, xfrag, indexes, x_f32, sim, outf);
}

// Round 3
// 230.331 us; speedup vs baseline: 1.3883x; 1.3883x over previous
//
#include <hip/hip_runtime.h>
#include <hip/hip_bf16.h>

#define NBANK 131072
#define DF 1024
#define NB 64

typedef float f32x4 __attribute__((ext_vector_type(4)));
typedef short bf16x8 __attribute__((ext_vector_type(8)));

__device__ __forceinline__ unsigned short f2bf(float f) {
    union { float f; unsigned u; } c; c.f = f;
    unsigned u = c.u;
    return (unsigned short)((u + 0x7FFFu + ((u >> 16) & 1u)) >> 16);
}

// Kernel A: L2-normalize the 64 input rows.
// Writes x_f32 (for the scatter update) and bf16 A-fragments pre-permuted
// into MFMA lane order: frag[(m>>4)*32 + ks][lane = (t&3)*16 + (m&15)].
__global__ __launch_bounds__(128) void knorm(const float* __restrict__ inputs,
                                             float* __restrict__ x_f32,
                                             bf16x8* __restrict__ xfrag) {
    int m = blockIdx.x;
    int t = threadIdx.x;          // handles k = t*8 .. t*8+7
    const f32x4* row = (const f32x4*)(inputs + (size_t)m * DF);
    f32x4 v0 = row[t * 2];
    f32x4 v1 = row[t * 2 + 1];
    float s = v0.x*v0.x + v0.y*v0.y + v0.z*v0.z + v0.w*v0.w
            + v1.x*v1.x + v1.y*v1.y + v1.z*v1.z + v1.w*v1.w;
    for (int o = 32; o > 0; o >>= 1) s += __shfl_xor(s, o);
    __shared__ float red[2];
    if ((t & 63) == 0) red[t >> 6] = s;
    __syncthreads();
    float tot = red[0] + red[1];
    float inv = 1.0f / fmaxf(sqrtf(tot), 1e-12f);
    v0 *= inv; v1 *= inv;
    f32x4* xr = (f32x4*)(x_f32 + (size_t)m * DF);
    xr[t * 2]     = v0;
    xr[t * 2 + 1] = v1;
    unsigned short h[8] = { f2bf(v0.x), f2bf(v0.y), f2bf(v0.z), f2bf(v0.w),
                            f2bf(v1.x), f2bf(v1.y), f2bf(v1.z), f2bf(v1.w) };
    int idx = ((m >> 4) * 32 + (t >> 2)) * 64 + (t & 3) * 16 + (m & 15);
    xfrag[idx] = *(bf16x8*)h;
}

// Kernel B: fused sim GEMM + bank copy + sequential momentum update.
// Per block: 16 bank rows. Phase 1: burst-load all 16 row-chunks into regs
// (16 independent dwordx4 in flight -> deep MLP), then copy-store to d_out
// (nontemporal) and pack bf16 into the XOR-swizzled LDS tile. Phase 2: 4
// waves x 32 K-steps of mfma 16x16x32 bf16 -> sim. Phase 3: blocks owning
// rows in `indexes` replay the exact sequential momentum chain (uniform
// branches; block-wide norm reduction), overwriting their own copy-stores
// (same thread, same address -> program order suffices).
__global__ __launch_bounds__(256) void kmain(const float* __restrict__ features,
                                             const bf16x8* __restrict__ xfrag,
                                             const int* __restrict__ indexes,
                                             const float* __restrict__ x_f32,
                                             float* __restrict__ sim,
                                             float* __restrict__ outf) {
    __shared__ __align__(16) unsigned char tile[16 * 2048];
    __shared__ float red[4];
    int j0 = blockIdx.x * 16;
    int t = threadIdx.x;          // covers cols t*4 .. t*4+3 of each row

    // which of my 16 rows appear in indexes? (uniform across block)
    unsigned urmask = 0;
#pragma unroll 8
    for (int j = 0; j < NB; ++j) {
        unsigned d = (unsigned)(indexes[j] - j0);
        if (d < 16u) urmask |= (1u << d);
    }

    // Phase 1a: burst all 16 loads (deep MLP)
    f32x4 v[16];
#pragma unroll
    for (int p = 0; p < 16; ++p)
        v[p] = *((const f32x4*)(features + (size_t)(j0 + p) * DF) + t);
    // Phase 1b: copy-store + bf16 pack + swizzled LDS write
#pragma unroll
    for (int p = 0; p < 16; ++p) {
        __builtin_nontemporal_store(v[p], (f32x4*)(outf + (size_t)(j0 + p) * DF) + t);
        unsigned lo = (unsigned)f2bf(v[p].x) | ((unsigned)f2bf(v[p].y) << 16);
        unsigned hi = (unsigned)f2bf(v[p].z) | ((unsigned)f2bf(v[p].w) << 16);
        uint2 pk; pk.x = lo; pk.y = hi;
        unsigned off = (unsigned)(p * 2048) + (((unsigned)(t * 8)) ^ ((unsigned)(p & 7) << 4));
        *(uint2*)(tile + off) = pk;
    }
    __syncthreads();

    // Phase 2: MFMA
    int wave = t >> 6;
    int lane = t & 63;
    const bf16x8* af = xfrag + (size_t)(wave * 32) * 64 + lane;
    unsigned brow = lane & 15;
    unsigned bbase = brow * 2048;
    unsigned bswz = (brow & 7) << 4;
    unsigned bcol = (unsigned)(lane >> 4) * 16;
    f32x4 acc = {0.f, 0.f, 0.f, 0.f};
#pragma unroll 8
    for (int ks = 0; ks < 32; ++ks) {
        bf16x8 a = af[ks * 64];
        bf16x8 b = *(const bf16x8*)(tile + bbase + (((unsigned)(ks * 64) + bcol) ^ bswz));
        acc = __builtin_amdgcn_mfma_f32_16x16x32_bf16(a, b, acc, 0, 0, 0);
    }
    int m0 = wave * 16 + (lane >> 4) * 4;
    int n = j0 + (lane & 15);
#pragma unroll
    for (int r = 0; r < 4; ++r)
        __builtin_nontemporal_store(acc[r] * 20.0f,
                                    sim + (size_t)(m0 + r) * NBANK + n);

    // Phase 3: sequential momentum chain for owned update rows
    if (urmask) {
        for (int p = 0; p < 16; ++p) {
            if (!((urmask >> p) & 1)) continue;      // uniform
            int row = j0 + p;
            f32x4 cur = *((const f32x4*)(features + (size_t)row * DF) + t);  // L2-hot
            for (int j = 0; j < NB; ++j) {
                if (indexes[j] != row) continue;     // uniform
                f32x4 xv = *((const f32x4*)(x_f32 + (size_t)j * DF) + t);
                cur = cur * 0.2f + xv * 0.8f;
                float s = cur.x*cur.x + cur.y*cur.y + cur.z*cur.z + cur.w*cur.w;
                for (int o = 32; o > 0; o >>= 1) s += __shfl_xor(s, o);
                if ((t & 63) == 0) red[t >> 6] = s;
                __syncthreads();
                float tot = red[0] + red[1] + red[2] + red[3];
                __syncthreads();
                float inv = 1.0f / fmaxf(sqrtf(tot), 1e-12f);
                cur *= inv;
            }
            *((f32x4*)(outf + (size_t)row * DF) + t) = cur;
        }
    }
}

extern "C" void kernel_launch(void* const* d_in, const int* in_sizes, int n_in,
                              void* d_out, int out_size, void* d_ws, size_t ws_size,
                              hipStream_t stream) {
    const float* inputs   = (const float*)d_in[0];
    const int*   indexes  = (const int*)d_in[1];
    const float* features = (const float*)d_in[2];
    float* sim  = (float*)d_out;                       // [64 * 131072]
    float* outf = sim + (size_t)NB * NBANK;            // [131072 * 1024]
    float*  x_f32 = (float*)d_ws;                      // 256 KB
    bf16x8* xfrag = (bf16x8*)((char*)d_ws + (size_t)NB * DF * 4);  // 128 KB

    knorm<<<NB, 128, 0, stream>>>(inputs, x_f32, xfrag);
    kmain<<<NBANK / 16, 256, 0, stream>>>(features, xfrag, indexes, x_f32, sim, outf);
}